// Round 1
// baseline (140.420 us; speedup 1.0000x reference)
//
#include <hip/hip_runtime.h>
#include <hip/hip_bf16.h>
#include <cstdint>

typedef __attribute__((ext_vector_type(4))) int i32x4;

#define XROWS 14
#define XW    24
#define XCI   80              // padded ci stride in bytes (64 data + 16 pad)
#define XROWB (XW * XCI)      // 1920 bytes per input row
#define HO_T  8
#define WO_T  16

__device__ __forceinline__ void g2lds16(const void* g, void* l) {
  __builtin_amdgcn_global_load_lds(
      (const __attribute__((address_space(1))) unsigned int*)g,
      (__attribute__((address_space(3))) unsigned int*)l, 16, 0, 0);
}

// Pack W7 (reconstructed from w1/w2/w3) into int8, layout per 7x7 slice s=kh*7+kw:
//   wb[((s*4 + g)*128 + co)*16 + lo]  with ci = g*16 + lo
__global__ void prep_w(const float* __restrict__ w1,
                       const float* __restrict__ w2,
                       const float* __restrict__ w3,
                       signed char* __restrict__ wb) {
  int t = blockIdx.x * 256 + threadIdx.x;   // 49*8192 total
  int lo = t & 15;
  int co = (t >> 4) & 127;
  int g  = (t >> 11) & 3;
  int s  = t >> 13;
  if (s >= 49) return;
  int kh = s / 7, kw = s % 7;
  int ci = g * 16 + lo;
  int base = ((co * 64 + ci) * 7 + kh) * 3;
  float v;
  if (kw < 3)       v = w1[base + kw];
  else if (kw == 3) v = w2[base + 1];
  else              v = w3[base + kw - 4];
  wb[t] = (signed char)(int)v;
}

__global__ __launch_bounds__(256, 2)
void conv7(const int* __restrict__ x,
           const signed char* __restrict__ wb,
           float* __restrict__ out) {
  __shared__ __align__(16) unsigned char Xs[XROWS * XROWB];   // 26880 B
  __shared__ __align__(16) unsigned char Ws[2][8192];         // 16384 B

  const int tid  = threadIdx.x;
  const int lane = tid & 63;
  const int wid  = tid >> 6;
  const int lrow = lane & 15;
  const int lkg  = lane >> 4;
  const int n       = blockIdx.z;
  const int ho_base = blockIdx.y * HO_T;
  const int wo_base = blockIdx.x * WO_T;

  // ---- stage X: [row r][w][ci] int8, transposed from NCHW, clamped to [0,7]
  {
    const int ci = tid >> 2;
    const int* xc = x + (size_t)(n * 64 + ci) * 112 * 112;
    for (int r = 0; r < XROWS; ++r) {
      int h = ho_base + r; h = h < 112 ? h : 111;          // clamp: rows >=112 only feed masked outputs
      const int* xrow = xc + h * 112;
      for (int sl = (tid & 3); sl < 6; sl += 4) {
        int wg = wo_base + sl * 4; wg = wg < 109 ? wg : 108; // clamp: tail slots only feed masked outputs
        const int4 v = *(const int4*)(xrow + wg);
        unsigned char* d = &Xs[r * XROWB + (sl * 4) * XCI + ci];
        int a0 = v.x, a1 = v.y, a2 = v.z, a3 = v.w;
        a0 = a0 < 0 ? 0 : (a0 > 7 ? 7 : a0);
        a1 = a1 < 0 ? 0 : (a1 > 7 ? 7 : a1);
        a2 = a2 < 0 ? 0 : (a2 > 7 ? 7 : a2);
        a3 = a3 < 0 ? 0 : (a3 > 7 ? 7 : a3);
        d[0]       = (unsigned char)a0;
        d[XCI]     = (unsigned char)a1;
        d[2 * XCI] = (unsigned char)a2;
        d[3 * XCI] = (unsigned char)a3;
      }
    }
  }
  // ---- stage W slice 0 into Ws[0] (async, drained by the syncthreads below)
  {
    #pragma unroll
    for (int r = 0; r < 2; ++r) {
      int c = r * 4 + wid;                                  // 0..7 chunks of 1 KiB
      g2lds16(wb + c * 1024 + lane * 16, &Ws[0][c * 1024 + lane * 16]);
    }
  }
  __syncthreads();

  const int co_half = wid >> 1;                             // wave grid: [2 co][2 spatial]
  const int sp_half = wid & 1;
  const int aOff  = (lkg * 128 + co_half * 64 + lrow) * 16; // bytes into W slice
  const int bOff  = lrow * XCI + lkg * 16;                  // bytes into X row
  const int spRow = sp_half * 4;

  i32x4 acc[4][4];
  #pragma unroll
  for (int m = 0; m < 4; ++m)
    #pragma unroll
    for (int b = 0; b < 4; ++b)
      acc[m][b] = (i32x4){0, 0, 0, 0};

  int s = 0;
  for (int kh = 0; kh < 7; ++kh) {
    for (int kw = 0; kw < 7; ++kw, ++s) {
      const unsigned char* wbuf = &Ws[s & 1][0];
      if (s < 48) {                                         // prefetch next slice into other buffer
        const signed char* nxt = wb + (s + 1) * 8192;
        #pragma unroll
        for (int r = 0; r < 2; ++r) {
          int c = r * 4 + wid;
          g2lds16(nxt + c * 1024 + lane * 16, &Ws[(s & 1) ^ 1][c * 1024 + lane * 16]);
        }
      }
      i32x4 A[4], B[4];
      #pragma unroll
      for (int m = 0; m < 4; ++m)
        A[m] = *(const i32x4*)(wbuf + aOff + m * 256);
      #pragma unroll
      for (int b = 0; b < 4; ++b)
        B[b] = *(const i32x4*)(&Xs[(spRow + b + kh) * XROWB + kw * XCI + bOff]);
      #pragma unroll
      for (int m = 0; m < 4; ++m)
        #pragma unroll
        for (int b = 0; b < 4; ++b)
          acc[m][b] = __builtin_amdgcn_mfma_i32_16x16x64_i8(A[m], B[b], acc[m][b], 0, 0, 0);
      __syncthreads();
    }
  }

  // ---- epilogue: C/D map col=lane&15 (wo), row=(lane>>4)*4+j (co); i32 -> f32 exact
  const int wo = wo_base + lrow;
  if (wo < 106) {
    #pragma unroll
    for (int m = 0; m < 4; ++m) {
      const int co = co_half * 64 + m * 16 + lkg * 4;
      #pragma unroll
      for (int b = 0; b < 4; ++b) {
        const int ho = ho_base + spRow + b;
        if (ho < 106) {
          float* op = out + (((size_t)n * 128 + co) * 106 + ho) * 106 + wo;
          #pragma unroll
          for (int j = 0; j < 4; ++j)
            op[(size_t)j * 11236] = (float)acc[m][b][j];
        }
      }
    }
  }
}

extern "C" void kernel_launch(void* const* d_in, const int* in_sizes, int n_in,
                              void* d_out, int out_size, void* d_ws, size_t ws_size,
                              hipStream_t stream) {
  const int*   x  = (const int*)d_in[0];
  const float* w1 = (const float*)d_in[1];
  const float* w2 = (const float*)d_in[2];
  const float* w3 = (const float*)d_in[3];
  float* outp = (float*)d_out;
  signed char* wbp = (signed char*)d_ws;   // needs 49*8192 = 401408 B of scratch

  prep_w<<<dim3(1568), dim3(256), 0, stream>>>(w1, w2, w3, wbp);
  conv7<<<dim3(7, 14, 16), dim3(256), 0, stream>>>(x, wbp, outp);
}